// Round 1
// baseline (12946.796 us; speedup 1.0000x reference)
//
#include <hip/hip_runtime.h>
#include <math.h>

#define H 128
#define W 128
#define HW (H*W)
#define NEV 200000
#define NFR 16

// ---------------- utility ----------------
__global__ void zero_kernel(float* __restrict__ p, int n) {
  int i = blockIdx.x * blockDim.x + threadIdx.x;
  int stride = gridDim.x * blockDim.x;
  for (; i < n; i += stride) p[i] = 0.0f;
}

// ---------------- per-frame t min/max ----------------
__global__ __launch_bounds__(256) void minmax_kernel(const float* __restrict__ t,
                                                     float* __restrict__ mm) {
  int f = blockIdx.x;
  const float* tf = t + (size_t)f * NEV;
  float mn = 1e30f, mx = -1e30f;
  for (int i = threadIdx.x; i < NEV; i += 256) {
    float v = tf[i];
    mn = fminf(mn, v);
    mx = fmaxf(mx, v);
  }
  __shared__ float smn[256], smx[256];
  smn[threadIdx.x] = mn; smx[threadIdx.x] = mx;
  __syncthreads();
  for (int s = 128; s > 0; s >>= 1) {
    if (threadIdx.x < s) {
      smn[threadIdx.x] = fminf(smn[threadIdx.x], smn[threadIdx.x + s]);
      smx[threadIdx.x] = fmaxf(smx[threadIdx.x], smx[threadIdx.x + s]);
    }
    __syncthreads();
  }
  if (threadIdx.x == 0) {
    float start = smn[0];
    float dur = fmaxf(smx[0] - start, 1.0f);
    mm[f * 2 + 0] = start;
    mm[f * 2 + 1] = 1.0f / dur;
  }
}

// ---------------- event scatter ----------------
__global__ __launch_bounds__(256) void scatter_kernel(const int* __restrict__ xy,
                                                      const float* __restrict__ t,
                                                      const float* __restrict__ p,
                                                      const float* __restrict__ mm,
                                                      float* __restrict__ rep) {
  int i = blockIdx.x * blockDim.x + threadIdx.x;
  const int total = NFR * NEV;
  if (i >= total) return;
  int f = i / NEV;
  int x = xy[2 * (size_t)i + 0];
  int y = xy[2 * (size_t)i + 1];
  x = min(max(x, 0), W - 1);
  y = min(max(y, 0), H - 1);
  int lin = y * W + x;
  float start = mm[f * 2 + 0];
  float invd  = mm[f * 2 + 1];
  float nt = (t[i] - start) * invd;
  nt = fminf(fmaxf(nt, 0.0f), 1.0f);
  bool pos = p[i] > 0.0f;
  float* base = rep + (size_t)f * 5 * HW;
  // count maps (ch 0 = pos, ch 1 = neg)
  atomicAdd(base + (pos ? 0 : HW) + lin, 1.0f);
  // latest maps (ch 2 = pos, ch 3 = neg); nt >= 0 so uint-bit max == float max
  atomicMax((unsigned int*)(base + (pos ? 2 : 3) * HW) + lin, __float_as_uint(nt));
  // occupancy (ch 4)
  base[4 * HW + lin] = 1.0f;
}

// ---------------- log1p + max-normalize count maps ----------------
__global__ __launch_bounds__(256) void norm_counts_kernel(float* __restrict__ rep) {
  int f = blockIdx.x >> 1;
  int ch = blockIdx.x & 1;
  float* ptr = rep + ((size_t)f * 5 + ch) * HW;
  float mx = 0.0f;
  for (int i = threadIdx.x; i < HW; i += 256) {
    float v = log1pf(ptr[i]);
    ptr[i] = v;
    mx = fmaxf(mx, v);
  }
  __shared__ float smx[256];
  smx[threadIdx.x] = mx;
  __syncthreads();
  for (int s = 128; s > 0; s >>= 1) {
    if (threadIdx.x < s)
      smx[threadIdx.x] = fmaxf(smx[threadIdx.x], smx[threadIdx.x + s]);
    __syncthreads();
  }
  float m = fmaxf(smx[0], 1.0f);
  for (int i = threadIdx.x; i < HW; i += 256) ptr[i] = ptr[i] / m;
}

// ---------------- direct 3x3 conv (SAME, stride 1) ----------------
template <int CIN>
__global__ __launch_bounds__(256) void conv3x3_kernel(const float* __restrict__ in,
                                                      const float* __restrict__ w,
                                                      const float* __restrict__ b,
                                                      float* __restrict__ out,
                                                      int cout) {
  int oc = blockIdx.z % cout;
  int f  = blockIdx.z / cout;
  __shared__ float wl[CIN * 9];
  int tid = threadIdx.y * 16 + threadIdx.x;
  for (int i = tid; i < CIN * 9; i += 256) wl[i] = w[(size_t)oc * CIN * 9 + i];
  __syncthreads();
  int x = blockIdx.x * 16 + threadIdx.x;
  int y = blockIdx.y * 16 + threadIdx.y;
  const float* inf = in + (size_t)f * CIN * HW;
  float acc = b[oc];
  for (int ic = 0; ic < CIN; ic++) {
    const float* ip = inf + (size_t)ic * HW;
    const float* wp = wl + ic * 9;
#pragma unroll
    for (int dy = -1; dy <= 1; dy++) {
      int yy = y + dy;
      if (yy < 0 || yy >= H) continue;
#pragma unroll
      for (int dx = -1; dx <= 1; dx++) {
        int xx = x + dx;
        if (xx < 0 || xx >= W) continue;
        acc += ip[yy * W + xx] * wp[(dy + 1) * 3 + (dx + 1)];
      }
    }
  }
  out[((size_t)f * cout + oc) * HW + y * W + x] = acc;
}

// ---------------- group-norm statistics (8 groups of 8 channels) ----------------
__global__ __launch_bounds__(256) void gn_stats_kernel(const float* __restrict__ h,
                                                       float* __restrict__ stats) {
  int f = blockIdx.x >> 3;
  int g = blockIdx.x & 7;
  const float* p = h + ((size_t)f * 64 + (size_t)g * 8) * HW;
  double sd = 0.0, ssd = 0.0;
  const int M = 8 * HW;
  for (int i = threadIdx.x; i < M; i += 256) {
    float v = p[i];
    sd += v;
    ssd += (double)v * (double)v;
  }
  __shared__ double s1[256], s2[256];
  s1[threadIdx.x] = sd; s2[threadIdx.x] = ssd;
  __syncthreads();
  for (int s = 128; s > 0; s >>= 1) {
    if (threadIdx.x < s) {
      s1[threadIdx.x] += s1[threadIdx.x + s];
      s2[threadIdx.x] += s2[threadIdx.x + s];
    }
    __syncthreads();
  }
  if (threadIdx.x == 0) {
    double Md = (double)M;
    double mu = s1[0] / Md;
    double var = s2[0] / Md - mu * mu;
    stats[blockIdx.x * 2 + 0] = (float)mu;
    stats[blockIdx.x * 2 + 1] = rsqrtf((float)var + 1e-5f);
  }
}

// ---------------- apply GN + exact GELU (in place) ----------------
__global__ __launch_bounds__(256) void gn_gelu_kernel(float* __restrict__ h,
                                                      const float* __restrict__ stats,
                                                      const float* __restrict__ sc,
                                                      const float* __restrict__ bi) {
  unsigned int i = blockIdx.x * blockDim.x + threadIdx.x;
  const unsigned int total = (unsigned int)NFR * 64u * HW;
  if (i >= total) return;
  unsigned int c = (i / HW) & 63u;
  unsigned int f = i / (64u * HW);
  unsigned int g = c >> 3;
  float mu = stats[(f * 8 + g) * 2 + 0];
  float rs = stats[(f * 8 + g) * 2 + 1];
  float v = (h[i] - mu) * rs * sc[c] + bi[c];
  float ge = 0.5f * v * (1.0f + erff(v * 0.70710678118654752440f));
  h[i] = ge;
}

// ---------------- launcher ----------------
extern "C" void kernel_launch(void* const* d_in, const int* in_sizes, int n_in,
                              void* d_out, int out_size, void* d_ws, size_t ws_size,
                              hipStream_t stream) {
  const int*   xy  = (const int*)d_in[0];
  const float* t   = (const float*)d_in[1];
  const float* p   = (const float*)d_in[2];
  // d_in[3] = height, d_in[4] = width (compile-time constants here)
  const float* w1  = (const float*)d_in[5];
  const float* b1  = (const float*)d_in[6];
  const float* g1s = (const float*)d_in[7];
  const float* g1b = (const float*)d_in[8];
  const float* w2  = (const float*)d_in[9];
  const float* b2  = (const float*)d_in[10];
  const float* g2s = (const float*)d_in[11];
  const float* g2b = (const float*)d_in[12];
  const float* w3  = (const float*)d_in[13];
  const float* b3  = (const float*)d_in[14];
  float* out = (float*)d_out;

  const size_t repN = (size_t)NFR * 5 * HW;   // 1,310,720 floats
  const size_t hN   = (size_t)NFR * 64 * HW;  // 16,777,216 floats

  float* ws    = (float*)d_ws;
  float* rep   = ws;
  float* mm    = ws + repN;         // 32 floats
  float* stats = mm + 64;           // 256 floats used
  float* h2    = stats + 512;
  float* h1;
  const size_t need_full = (repN + 64 + 512 + 2 * hN) * sizeof(float);
  if (ws_size >= need_full) {
    h1 = h2 + hN;
  } else {
    // h1 lives in d_out scratch space; it is dead before conv3 overwrites d_out
    h1 = out;
  }

  dim3 b256(256);
  // 1) zero the event representation buffer
  zero_kernel<<<2048, b256, 0, stream>>>(rep, (int)repN);
  // 2) per-frame min/max of t
  minmax_kernel<<<NFR, b256, 0, stream>>>(t, mm);
  // 3) scatter events
  scatter_kernel<<<(NFR * NEV + 255) / 256, b256, 0, stream>>>(xy, t, p, mm, rep);
  // 4) log1p + max-normalize count channels
  norm_counts_kernel<<<NFR * 2, b256, 0, stream>>>(rep);

  dim3 cblk(16, 16);
  // 5) conv1: 5 -> 64
  conv3x3_kernel<5><<<dim3(W / 16, H / 16, NFR * 64), cblk, 0, stream>>>(rep, w1, b1, h1, 64);
  // 6) GN1 stats + apply + GELU
  gn_stats_kernel<<<NFR * 8, b256, 0, stream>>>(h1, stats);
  gn_gelu_kernel<<<(unsigned int)((hN + 255) / 256), b256, 0, stream>>>(h1, stats, g1s, g1b);
  // 7) conv2: 64 -> 64
  conv3x3_kernel<64><<<dim3(W / 16, H / 16, NFR * 64), cblk, 0, stream>>>(h1, w2, b2, h2, 64);
  // 8) GN2 stats + apply + GELU
  gn_stats_kernel<<<NFR * 8, b256, 0, stream>>>(h2, stats);
  gn_gelu_kernel<<<(unsigned int)((hN + 255) / 256), b256, 0, stream>>>(h2, stats, g2s, g2b);
  // 9) conv3: 64 -> 256, straight into d_out
  conv3x3_kernel<64><<<dim3(W / 16, H / 16, NFR * 256), cblk, 0, stream>>>(h2, w3, b3, out, 256);
}

// Round 2
// 1610.172 us; speedup vs baseline: 8.0406x; 8.0406x over previous
//
#include <hip/hip_runtime.h>
#include <math.h>

#define H 128
#define W 128
#define HW (H*W)
#define NEV 200000
#define NFR 16

typedef __attribute__((ext_vector_type(8))) __bf16 bf16x8;
typedef __attribute__((ext_vector_type(4))) float f32x4;
typedef __attribute__((ext_vector_type(4))) int   i32x4;

__device__ inline unsigned short f2bfbits(float f) {
  union { float f; unsigned u; } v; v.f = f;
  return (unsigned short)((v.u + 0x7FFFu + ((v.u >> 16) & 1u)) >> 16);
}

// ---------------- utility ----------------
__global__ void zero_kernel(float* __restrict__ p, int n) {
  int i = blockIdx.x * blockDim.x + threadIdx.x;
  int stride = gridDim.x * blockDim.x;
  for (; i < n; i += stride) p[i] = 0.0f;
}

// ---------------- per-frame t min/max ----------------
__global__ __launch_bounds__(256) void minmax_kernel(const float* __restrict__ t,
                                                     float* __restrict__ mm) {
  int f = blockIdx.x;
  const float* tf = t + (size_t)f * NEV;
  float mn = 1e30f, mx = -1e30f;
  for (int i = threadIdx.x; i < NEV; i += 256) {
    float v = tf[i];
    mn = fminf(mn, v);
    mx = fmaxf(mx, v);
  }
  __shared__ float smn[256], smx[256];
  smn[threadIdx.x] = mn; smx[threadIdx.x] = mx;
  __syncthreads();
  for (int s = 128; s > 0; s >>= 1) {
    if (threadIdx.x < s) {
      smn[threadIdx.x] = fminf(smn[threadIdx.x], smn[threadIdx.x + s]);
      smx[threadIdx.x] = fmaxf(smx[threadIdx.x], smx[threadIdx.x + s]);
    }
    __syncthreads();
  }
  if (threadIdx.x == 0) {
    float start = smn[0];
    float dur = fmaxf(smx[0] - start, 1.0f);
    mm[f * 2 + 0] = start;
    mm[f * 2 + 1] = 1.0f / dur;
  }
}

// ---------------- event scatter ----------------
__global__ __launch_bounds__(256) void scatter_kernel(const int* __restrict__ xy,
                                                      const float* __restrict__ t,
                                                      const float* __restrict__ p,
                                                      const float* __restrict__ mm,
                                                      float* __restrict__ rep) {
  int i = blockIdx.x * blockDim.x + threadIdx.x;
  const int total = NFR * NEV;
  if (i >= total) return;
  int f = i / NEV;
  int x = xy[2 * (size_t)i + 0];
  int y = xy[2 * (size_t)i + 1];
  x = min(max(x, 0), W - 1);
  y = min(max(y, 0), H - 1);
  int lin = y * W + x;
  float start = mm[f * 2 + 0];
  float invd  = mm[f * 2 + 1];
  float nt = (t[i] - start) * invd;
  nt = fminf(fmaxf(nt, 0.0f), 1.0f);
  bool pos = p[i] > 0.0f;
  float* base = rep + (size_t)f * 5 * HW;
  atomicAdd(base + (pos ? 0 : HW) + lin, 1.0f);
  atomicMax((unsigned int*)(base + (pos ? 2 : 3) * HW) + lin, __float_as_uint(nt));
  base[4 * HW + lin] = 1.0f;
}

// ---------------- log1p + max-normalize count maps ----------------
__global__ __launch_bounds__(256) void norm_counts_kernel(float* __restrict__ rep) {
  int f = blockIdx.x >> 1;
  int ch = blockIdx.x & 1;
  float* ptr = rep + ((size_t)f * 5 + ch) * HW;
  float mx = 0.0f;
  for (int i = threadIdx.x; i < HW; i += 256) {
    float v = log1pf(ptr[i]);
    ptr[i] = v;
    mx = fmaxf(mx, v);
  }
  __shared__ float smx[256];
  smx[threadIdx.x] = mx;
  __syncthreads();
  for (int s = 128; s > 0; s >>= 1) {
    if (threadIdx.x < s)
      smx[threadIdx.x] = fmaxf(smx[threadIdx.x], smx[threadIdx.x + s]);
    __syncthreads();
  }
  float m = fmaxf(smx[0], 1.0f);
  for (int i = threadIdx.x; i < HW; i += 256) ptr[i] = ptr[i] / m;
}

// ---------------- direct 3x3 conv for conv1 (5 input channels) ----------------
template <int CIN>
__global__ __launch_bounds__(256) void conv3x3_kernel(const float* __restrict__ in,
                                                      const float* __restrict__ w,
                                                      const float* __restrict__ b,
                                                      float* __restrict__ out,
                                                      int cout) {
  int oc = blockIdx.z % cout;
  int f  = blockIdx.z / cout;
  __shared__ float wl[CIN * 9];
  int tid = threadIdx.y * 16 + threadIdx.x;
  for (int i = tid; i < CIN * 9; i += 256) wl[i] = w[(size_t)oc * CIN * 9 + i];
  __syncthreads();
  int x = blockIdx.x * 16 + threadIdx.x;
  int y = blockIdx.y * 16 + threadIdx.y;
  const float* inf = in + (size_t)f * CIN * HW;
  float acc = b[oc];
  for (int ic = 0; ic < CIN; ic++) {
    const float* ip = inf + (size_t)ic * HW;
    const float* wp = wl + ic * 9;
#pragma unroll
    for (int dy = -1; dy <= 1; dy++) {
      int yy = y + dy;
      if (yy < 0 || yy >= H) continue;
#pragma unroll
      for (int dx = -1; dx <= 1; dx++) {
        int xx = x + dx;
        if (xx < 0 || xx >= W) continue;
        acc += ip[yy * W + xx] * wp[(dy + 1) * 3 + (dx + 1)];
      }
    }
  }
  out[((size_t)f * cout + oc) * HW + y * W + x] = acc;
}

// ---------------- group-norm statistics (8 groups of 8 channels) ----------------
__global__ __launch_bounds__(256) void gn_stats_kernel(const float* __restrict__ h,
                                                       float* __restrict__ stats) {
  int f = blockIdx.x >> 3;
  int g = blockIdx.x & 7;
  const float* p = h + ((size_t)f * 64 + (size_t)g * 8) * HW;
  double sd = 0.0, ssd = 0.0;
  const int M = 8 * HW;
  for (int i = threadIdx.x; i < M; i += 256) {
    float v = p[i];
    sd += v;
    ssd += (double)v * (double)v;
  }
  __shared__ double s1[256], s2[256];
  s1[threadIdx.x] = sd; s2[threadIdx.x] = ssd;
  __syncthreads();
  for (int s = 128; s > 0; s >>= 1) {
    if (threadIdx.x < s) {
      s1[threadIdx.x] += s1[threadIdx.x + s];
      s2[threadIdx.x] += s2[threadIdx.x + s];
    }
    __syncthreads();
  }
  if (threadIdx.x == 0) {
    double Md = (double)M;
    double mu = s1[0] / Md;
    double var = s2[0] / Md - mu * mu;
    stats[blockIdx.x * 2 + 0] = (float)mu;
    stats[blockIdx.x * 2 + 1] = rsqrtf((float)var + 1e-5f);
  }
}

// ---------------- GN + GELU + NCHW fp32 -> NHWC bf16 transpose ----------------
__global__ __launch_bounds__(256) void gn_gelu_t_kernel(const float* __restrict__ h,
                                                        const float* __restrict__ stats,
                                                        const float* __restrict__ sc,
                                                        const float* __restrict__ bi,
                                                        short* __restrict__ hbf) {
  __shared__ short lds[256 * 64];
  const int f  = blockIdx.x >> 6;
  const int pb = (blockIdx.x & 63) << 8;   // pixel base (256 pixels per block)
  const int tid = threadIdx.x;
  const float* hp = h + (((size_t)f << 6) << 14) + pb + tid;
  const int t7 = tid & 7;
#pragma unroll
  for (int c8 = 0; c8 < 8; c8++) {
    unsigned short v[8];
#pragma unroll
    for (int j = 0; j < 8; j++) {
      const int c = (c8 << 3) + j;
      const float mu = stats[(((f << 3) + (c >> 3)) << 1) + 0];
      const float rs = stats[(((f << 3) + (c >> 3)) << 1) + 1];
      float x = (hp[(size_t)c << 14] - mu) * rs * sc[c] + bi[c];
      x = 0.5f * x * (1.0f + erff(x * 0.70710678118654752440f));
      v[j] = f2bfbits(x);
    }
    i32x4 pk;
    pk[0] = (int)v[0] | ((int)v[1] << 16);
    pk[1] = (int)v[2] | ((int)v[3] << 16);
    pk[2] = (int)v[4] | ((int)v[5] << 16);
    pk[3] = (int)v[6] | ((int)v[7] << 16);
    *reinterpret_cast<i32x4*>(&lds[(tid << 6) + ((c8 ^ t7) << 3)]) = pk;
  }
  __syncthreads();
#pragma unroll
  for (int k = 0; k < 8; k++) {
    const int chunk = (k << 8) + tid;
    const int pix = chunk >> 3, ck = chunk & 7;
    i32x4 v = *reinterpret_cast<const i32x4*>(&lds[(pix << 6) + ((ck ^ (pix & 7)) << 3)]);
    *reinterpret_cast<i32x4*>(&hbf[(((size_t)((f << 14) + pb + pix)) << 6) + (ck << 3)]) = v;
  }
}

// ---------------- weight repack: [OC][64][3][3] f32 -> [t][OC/16][c][lane][8] bf16 ----------------
template <int OC>
__global__ __launch_bounds__(256) void repack_w_kernel(const float* __restrict__ w,
                                                       short* __restrict__ wp) {
  constexpr int NOB16 = OC >> 4;
  const int i = blockIdx.x * 256 + threadIdx.x;
  constexpr int total = 9 * NOB16 * 2 * 512;
  if (i >= total) return;
  const int j = i & 7;
  const int l = (i >> 3) & 63;
  const int c = (i >> 9) & 1;
  const int rest = i >> 10;               // t*NOB16 + ob
  const int t = rest / NOB16;
  const int ob = rest - t * NOB16;
  const int oc = (ob << 4) + (l & 15);
  const int ic = (c << 5) + ((l >> 4) << 3) + j;
  wp[i] = (short)f2bfbits(w[((size_t)oc * 64 + ic) * 9 + t]);
}

// ---------------- MFMA implicit-GEMM 3x3 conv (64 in-ch, NHWC bf16 in, NCHW f32 out) ----------------
template <int OC>
__global__ __launch_bounds__(256) void conv_mfma_kernel(const short* __restrict__ xin,
                                                        const short* __restrict__ wp,
                                                        const float* __restrict__ bias,
                                                        float* __restrict__ out) {
  constexpr int NOB16 = OC >> 4;
  constexpr int NOB64 = OC >> 6;
  __shared__ short lds[324 * 64];          // 18x18 pixels x 64 ch, swizzled

  const int tx0 = blockIdx.x << 4;
  const int ty0 = blockIdx.y << 4;
  const int f     = blockIdx.z / NOB64;
  const int ocb64 = blockIdx.z % NOB64;

  const int tid = threadIdx.x;
  const short* src = xin + (((size_t)f << 14) << 6);

  // stage 18x18x64 bf16 tile, XOR-swizzled (slot = ck ^ (pix&7))
  for (int i = tid; i < 324 * 8; i += 256) {
    const int pix = i >> 3, ck = i & 7;
    const int sy = pix / 18;
    const int sx = pix - sy * 18;
    const int gy = ty0 + sy - 1, gx = tx0 + sx - 1;
    i32x4 v = {0, 0, 0, 0};
    if (gy >= 0 && gy < H && gx >= 0 && gx < W)
      v = *reinterpret_cast<const i32x4*>(src + ((((size_t)(gy << 7) + gx)) << 6) + (ck << 3));
    *reinterpret_cast<i32x4*>(&lds[(pix << 6) + ((ck ^ (pix & 7)) << 3)]) = v;
  }

  const int wid  = tid >> 6;
  const int lane = tid & 63;
  const int ob16 = ocb64 * 4 + wid;        // this wave's 16-oc block
  const int ox = lane & 15;
  const int kg = lane >> 4;

  // A fragments: 9 taps x 2 k-chunks, 16B coalesced per lane
  bf16x8 afrag[9][2];
#pragma unroll
  for (int t = 0; t < 9; t++)
#pragma unroll
    for (int c = 0; c < 2; c++)
      afrag[t][c] = __builtin_bit_cast(bf16x8,
        *reinterpret_cast<const i32x4*>(wp + ((((t * NOB16 + ob16) * 2 + c) << 9) + (lane << 3))));

  // accumulators init with bias
  const int rbase = ocb64 * 64 + wid * 16 + (kg << 2);
  f32x4 binit;
#pragma unroll
  for (int r = 0; r < 4; r++) binit[r] = bias[rbase + r];
  f32x4 acc[16];
#pragma unroll
  for (int i = 0; i < 16; i++) acc[i] = binit;

  __syncthreads();

  // main loop over the 18 input tile rows
#pragma unroll
  for (int iy = 0; iy < 18; iy++) {
    bf16x8 bfrag[3][2];
#pragma unroll
    for (int dx = 0; dx < 3; dx++) {
      const int p = iy * 18 + ox + dx;
#pragma unroll
      for (int c = 0; c < 2; c++) {
        const int kc = (c << 2) + kg;
        bfrag[dx][c] = __builtin_bit_cast(bf16x8,
          *reinterpret_cast<const i32x4*>(&lds[(p << 6) + ((kc ^ (p & 7)) << 3)]));
      }
    }
#pragma unroll
    for (int dy = 0; dy < 3; dy++) {
      const int oy = iy - dy;
      if (oy >= 0 && oy < 16) {
#pragma unroll
        for (int dx = 0; dx < 3; dx++)
#pragma unroll
          for (int c = 0; c < 2; c++)
            acc[oy] = __builtin_amdgcn_mfma_f32_16x16x32_bf16(
                afrag[dy * 3 + dx][c], bfrag[dx][c], acc[oy], 0, 0, 0);
      }
    }
  }

  // store: D row = oc (rbase + r), col = pixel ox
#pragma unroll
  for (int oy = 0; oy < 16; oy++) {
    const int pix = ((ty0 + oy) << 7) + tx0 + ox;
#pragma unroll
    for (int r = 0; r < 4; r++)
      out[(((size_t)(f * OC + rbase + r)) << 14) + pix] = acc[oy][r];
  }
}

// ---------------- launcher ----------------
extern "C" void kernel_launch(void* const* d_in, const int* in_sizes, int n_in,
                              void* d_out, int out_size, void* d_ws, size_t ws_size,
                              hipStream_t stream) {
  const int*   xy  = (const int*)d_in[0];
  const float* t   = (const float*)d_in[1];
  const float* p   = (const float*)d_in[2];
  const float* w1  = (const float*)d_in[5];
  const float* b1  = (const float*)d_in[6];
  const float* g1s = (const float*)d_in[7];
  const float* g1b = (const float*)d_in[8];
  const float* w2  = (const float*)d_in[9];
  const float* b2  = (const float*)d_in[10];
  const float* g2s = (const float*)d_in[11];
  const float* g2b = (const float*)d_in[12];
  const float* w3  = (const float*)d_in[13];
  const float* b3  = (const float*)d_in[14];
  float* out = (float*)d_out;

  const size_t repN = (size_t)NFR * 5 * HW;   // 1,310,720 floats
  const size_t hN   = (size_t)NFR * 64 * HW;  // 16,777,216 elements

  // workspace layout
  float* ws    = (float*)d_ws;
  float* rep   = ws;                       // 5.24 MB
  float* mm    = ws + repN;                // 64 floats
  float* stats = mm + 64;                  // 512 floats
  short* wpk2  = (short*)(stats + 512);    // 36,864 shorts
  short* wpk3  = wpk2 + 9 * 4 * 2 * 512;   // 147,456 shorts
  short* h2bf  = wpk3 + 9 * 16 * 2 * 512;  // hN shorts (32 MB), 16B aligned
  const size_t base_bytes = (repN + 576) * 4 + (36864 + 147456 + hN) * 2;
  short* h1bf;
  if (ws_size >= base_bytes + hN * 2) {
    h1bf = h2bf + hN;                      // fits in workspace
  } else {
    h1bf = (short*)(out + 2 * hN);         // out-tail scratch, dead before conv3
  }
  // fp32 intermediates live in d_out (dead before conv3 writes)
  float* h1f = out;
  float* h2f = out + hN;

  dim3 b256(256);
  // event representation
  zero_kernel<<<2048, b256, 0, stream>>>(rep, (int)repN);
  minmax_kernel<<<NFR, b256, 0, stream>>>(t, mm);
  scatter_kernel<<<(NFR * NEV + 255) / 256, b256, 0, stream>>>(xy, t, p, mm, rep);
  norm_counts_kernel<<<NFR * 2, b256, 0, stream>>>(rep);

  // weight repack (independent of the above)
  repack_w_kernel<64><<<(9 * 4 * 2 * 512 + 255) / 256, b256, 0, stream>>>(w2, wpk2);
  repack_w_kernel<256><<<(9 * 16 * 2 * 512 + 255) / 256, b256, 0, stream>>>(w3, wpk3);

  // conv1 (direct fp32): rep -> h1f
  dim3 cblk(16, 16);
  conv3x3_kernel<5><<<dim3(W / 16, H / 16, NFR * 64), cblk, 0, stream>>>(rep, w1, b1, h1f, 64);

  // GN1 + GELU -> NHWC bf16
  gn_stats_kernel<<<NFR * 8, b256, 0, stream>>>(h1f, stats);
  gn_gelu_t_kernel<<<NFR * 64, b256, 0, stream>>>(h1f, stats, g1s, g1b, h1bf);

  // conv2 (MFMA): h1bf -> h2f
  conv_mfma_kernel<64><<<dim3(8, 8, NFR), b256, 0, stream>>>(h1bf, wpk2, b2, h2f);

  // GN2 + GELU -> NHWC bf16
  gn_stats_kernel<<<NFR * 8, b256, 0, stream>>>(h2f, stats);
  gn_gelu_t_kernel<<<NFR * 64, b256, 0, stream>>>(h2f, stats, g2s, g2b, h2bf);

  // conv3 (MFMA): h2bf -> out
  conv_mfma_kernel<256><<<dim3(8, 8, NFR * 4), b256, 0, stream>>>(h2bf, wpk3, b3, out);
}

// Round 3
// 863.166 us; speedup vs baseline: 14.9992x; 1.8654x over previous
//
#include <hip/hip_runtime.h>
#include <math.h>

#define H 128
#define W 128
#define HW (H*W)
#define NEV 200000
#define NFR 16

typedef __attribute__((ext_vector_type(8))) __bf16 bf16x8;
typedef __attribute__((ext_vector_type(4))) float f32x4;
typedef __attribute__((ext_vector_type(4))) int   i32x4;

__device__ inline unsigned short f2bfbits(float f) {
  union { float f; unsigned u; } v; v.f = f;
  return (unsigned short)((v.u + 0x7FFFu + ((v.u >> 16) & 1u)) >> 16);
}

// ---------------- init: zero rep + stats, seed minmax atomics ----------------
__global__ void init_kernel(float* __restrict__ rep, unsigned* __restrict__ mm_u,
                            float* __restrict__ statsA, float* __restrict__ statsB) {
  int i = blockIdx.x * blockDim.x + threadIdx.x;
  int stride = gridDim.x * blockDim.x;
  const int repN = NFR * 5 * HW;
  for (int k = i; k < repN; k += stride) rep[k] = 0.0f;
  if (i < NFR) { mm_u[2 * i] = 0x7F800000u; mm_u[2 * i + 1] = 0u; }
  if (i < 256) { statsA[i] = 0.0f; statsB[i] = 0.0f; }
}

// ---------------- per-frame t min/max (two-stage, uint atomics) ----------------
__global__ __launch_bounds__(256) void minmax_kernel(const float* __restrict__ t,
                                                     unsigned* __restrict__ mm_u) {
  const int f = blockIdx.x >> 5;
  const int chunk = blockIdx.x & 31;
  const f32x4* t4 = (const f32x4*)(t + (size_t)f * NEV);
  float mn = 1e30f, mx = -1e30f;
  for (int i = chunk * 256 + threadIdx.x; i < NEV / 4; i += 32 * 256) {
    f32x4 v = t4[i];
    mn = fminf(mn, fminf(fminf(v[0], v[1]), fminf(v[2], v[3])));
    mx = fmaxf(mx, fmaxf(fmaxf(v[0], v[1]), fmaxf(v[2], v[3])));
  }
  __shared__ float smn[256], smx[256];
  smn[threadIdx.x] = mn; smx[threadIdx.x] = mx;
  __syncthreads();
  for (int s = 128; s > 0; s >>= 1) {
    if (threadIdx.x < s) {
      smn[threadIdx.x] = fminf(smn[threadIdx.x], smn[threadIdx.x + s]);
      smx[threadIdx.x] = fmaxf(smx[threadIdx.x], smx[threadIdx.x + s]);
    }
    __syncthreads();
  }
  if (threadIdx.x == 0) {
    atomicMin(&mm_u[2 * f + 0], __float_as_uint(smn[0]));
    atomicMax(&mm_u[2 * f + 1], __float_as_uint(smx[0]));
  }
}

// ---------------- event scatter ----------------
__global__ __launch_bounds__(256) void scatter_kernel(const int* __restrict__ xy,
                                                      const float* __restrict__ t,
                                                      const float* __restrict__ p,
                                                      const unsigned* __restrict__ mm_u,
                                                      float* __restrict__ rep) {
  int i = blockIdx.x * blockDim.x + threadIdx.x;
  const int total = NFR * NEV;
  if (i >= total) return;
  int f = i / NEV;
  int x = xy[2 * (size_t)i + 0];
  int y = xy[2 * (size_t)i + 1];
  x = min(max(x, 0), W - 1);
  y = min(max(y, 0), H - 1);
  int lin = y * W + x;
  float start = __uint_as_float(mm_u[2 * f + 0]);
  float endv  = __uint_as_float(mm_u[2 * f + 1]);
  float dur = fmaxf(endv - start, 1.0f);
  float nt = fminf(fmaxf((t[i] - start) / dur, 0.0f), 1.0f);
  bool pos = p[i] > 0.0f;
  float* base = rep + (size_t)f * 5 * HW;
  atomicAdd(base + (pos ? 0 : HW) + lin, 1.0f);
  atomicMax((unsigned int*)(base + (pos ? 2 : 3) * HW) + lin, __float_as_uint(nt));
  base[4 * HW + lin] = 1.0f;
}

// ---------------- log1p + max-normalize count maps ----------------
__global__ __launch_bounds__(256) void norm_counts_kernel(float* __restrict__ rep) {
  int f = blockIdx.x >> 1;
  int ch = blockIdx.x & 1;
  float* ptr = rep + ((size_t)f * 5 + ch) * HW;
  float mx = 0.0f;
  for (int i = threadIdx.x; i < HW; i += 256) {
    float v = log1pf(ptr[i]);
    ptr[i] = v;
    mx = fmaxf(mx, v);
  }
  __shared__ float smx[256];
  smx[threadIdx.x] = mx;
  __syncthreads();
  for (int s = 128; s > 0; s >>= 1) {
    if (threadIdx.x < s)
      smx[threadIdx.x] = fmaxf(smx[threadIdx.x], smx[threadIdx.x + s]);
    __syncthreads();
  }
  float m = fmaxf(smx[0], 1.0f);
  for (int i = threadIdx.x; i < HW; i += 256) ptr[i] = ptr[i] / m;
}

// ---------------- conv1: LDS-tiled direct 5->64, scalar-load weights ----------------
__global__ __launch_bounds__(256) void conv1_kernel(const float* __restrict__ rep,
                                                    const float* __restrict__ w,
                                                    const float* __restrict__ b,
                                                    float* __restrict__ out) {
  __shared__ float in_t[5][18][18];
  const int f = blockIdx.z;
  const int tx0 = blockIdx.x << 4, ty0 = blockIdx.y << 4;
  const int tid = threadIdx.x;
  for (int i = tid; i < 5 * 324; i += 256) {
    const int ic = i / 324, pix = i - ic * 324;
    const int sy = pix / 18, sx = pix - sy * 18;
    const int gy = ty0 + sy - 1, gx = tx0 + sx - 1;
    float v = 0.0f;
    if (gy >= 0 && gy < H && gx >= 0 && gx < W)
      v = rep[(((size_t)f * 5 + ic) << 14) + (gy << 7) + gx];
    in_t[ic][sy][sx] = v;
  }
  __syncthreads();
  const int tx = tid & 15, ty = tid >> 4;
  float xv[45];
#pragma unroll
  for (int ic = 0; ic < 5; ic++)
#pragma unroll
    for (int dy = 0; dy < 3; dy++)
#pragma unroll
      for (int dx = 0; dx < 3; dx++)
        xv[ic * 9 + dy * 3 + dx] = in_t[ic][ty + dy][tx + dx];
  const int pix = ((ty0 + ty) << 7) + tx0 + tx;
  float* op = out + ((size_t)f << 20) + pix;
  for (int oc = 0; oc < 64; oc++) {
    float acc = b[oc];
#pragma unroll
    for (int k = 0; k < 45; k++) acc += xv[k] * w[oc * 45 + k];
    op[(size_t)oc << 14] = acc;
  }
}

// ---------------- group-norm stats: two-stage (1024 blocks, float atomics) ----------------
__global__ __launch_bounds__(256) void gn_stats_kernel(const float* __restrict__ h,
                                                       float* __restrict__ stats) {
  const int fg = blockIdx.x >> 3;          // f*8+g
  const int s  = blockIdx.x & 7;
  const f32x4* p4 = (const f32x4*)(h + (size_t)fg * 8 * HW + s * 16384);
  float sum = 0.0f, ssq = 0.0f;
  for (int i = threadIdx.x; i < 4096; i += 256) {
    f32x4 v = p4[i];
    sum += (v[0] + v[1]) + (v[2] + v[3]);
    ssq += (v[0] * v[0] + v[1] * v[1]) + (v[2] * v[2] + v[3] * v[3]);
  }
  __shared__ float s1[256], s2[256];
  s1[threadIdx.x] = sum; s2[threadIdx.x] = ssq;
  __syncthreads();
  for (int s2i = 128; s2i > 0; s2i >>= 1) {
    if (threadIdx.x < s2i) {
      s1[threadIdx.x] += s1[threadIdx.x + s2i];
      s2[threadIdx.x] += s2[threadIdx.x + s2i];
    }
    __syncthreads();
  }
  if (threadIdx.x == 0) {
    atomicAdd(&stats[fg * 2 + 0], s1[0]);
    atomicAdd(&stats[fg * 2 + 1], s2[0]);
  }
}

// ---------------- GN + GELU + NCHW fp32 -> NHWC bf16 transpose ----------------
__global__ __launch_bounds__(256) void gn_gelu_t_kernel(const float* __restrict__ h,
                                                        const float* __restrict__ stats,
                                                        const float* __restrict__ sc,
                                                        const float* __restrict__ bi,
                                                        short* __restrict__ hbf) {
  __shared__ short lds[256 * 64];
  const int f  = blockIdx.x >> 6;
  const int pb = (blockIdx.x & 63) << 8;
  const int tid = threadIdx.x;
  const float inv = 1.0f / 131072.0f;
  float mu8[8], rs8[8];
#pragma unroll
  for (int g = 0; g < 8; g++) {
    float sm = stats[((f << 3) + g) * 2 + 0];
    float sq = stats[((f << 3) + g) * 2 + 1];
    float mu = sm * inv;
    float var = sq * inv - mu * mu;
    mu8[g] = mu;
    rs8[g] = rsqrtf(var + 1e-5f);
  }
  const float* hp = h + (((size_t)f << 6) << 14) + pb + tid;
  const int t7 = tid & 7;
#pragma unroll
  for (int c8 = 0; c8 < 8; c8++) {
    unsigned short v[8];
#pragma unroll
    for (int j = 0; j < 8; j++) {
      const int c = (c8 << 3) + j;
      const int g = c >> 3;
      float x = (hp[(size_t)c << 14] - mu8[g]) * rs8[g] * sc[c] + bi[c];
      x = 0.5f * x * (1.0f + erff(x * 0.70710678118654752440f));
      v[j] = f2bfbits(x);
    }
    i32x4 pk;
    pk[0] = (int)v[0] | ((int)v[1] << 16);
    pk[1] = (int)v[2] | ((int)v[3] << 16);
    pk[2] = (int)v[4] | ((int)v[5] << 16);
    pk[3] = (int)v[6] | ((int)v[7] << 16);
    *reinterpret_cast<i32x4*>(&lds[(tid << 6) + ((c8 ^ t7) << 3)]) = pk;
  }
  __syncthreads();
#pragma unroll
  for (int k = 0; k < 8; k++) {
    const int chunk = (k << 8) + tid;
    const int pix = chunk >> 3, ck = chunk & 7;
    i32x4 v = *reinterpret_cast<const i32x4*>(&lds[(pix << 6) + ((ck ^ (pix & 7)) << 3)]);
    *reinterpret_cast<i32x4*>(&hbf[(((size_t)((f << 14) + pb + pix)) << 6) + (ck << 3)]) = v;
  }
}

// ---------------- weight repack: [OC][64][3][3] f32 -> [t][OC/16][c][lane][8] bf16 ----------------
template <int OC>
__global__ __launch_bounds__(256) void repack_w_kernel(const float* __restrict__ w,
                                                       short* __restrict__ wp) {
  constexpr int NOB16 = OC >> 4;
  const int i = blockIdx.x * 256 + threadIdx.x;
  constexpr int total = 9 * NOB16 * 2 * 512;
  if (i >= total) return;
  const int j = i & 7;
  const int l = (i >> 3) & 63;
  const int c = (i >> 9) & 1;
  const int rest = i >> 10;
  const int t = rest / NOB16;
  const int ob = rest - t * NOB16;
  const int oc = (ob << 4) + (l & 15);
  const int ic = (c << 5) + ((l >> 4) << 3) + j;
  wp[i] = (short)f2bfbits(w[((size_t)oc * 64 + ic) * 9 + t]);
}

// ---------------- MFMA implicit-GEMM 3x3 conv (64 in-ch, NHWC bf16 in, NCHW f32 out) ----------------
template <int OC>
__global__ __launch_bounds__(256) void conv_mfma_kernel(const short* __restrict__ xin,
                                                        const short* __restrict__ wp,
                                                        const float* __restrict__ bias,
                                                        float* __restrict__ out) {
  constexpr int NOB16 = OC >> 4;
  constexpr int NOB64 = OC >> 6;
  __shared__ short lds[324 * 64];

  const int tx0 = blockIdx.x << 4;
  const int ty0 = blockIdx.y << 4;
  const int f     = blockIdx.z / NOB64;
  const int ocb64 = blockIdx.z % NOB64;

  const int tid = threadIdx.x;
  const short* src = xin + (((size_t)f << 14) << 6);

  for (int i = tid; i < 324 * 8; i += 256) {
    const int pix = i >> 3, ck = i & 7;
    const int sy = pix / 18;
    const int sx = pix - sy * 18;
    const int gy = ty0 + sy - 1, gx = tx0 + sx - 1;
    i32x4 v = {0, 0, 0, 0};
    if (gy >= 0 && gy < H && gx >= 0 && gx < W)
      v = *reinterpret_cast<const i32x4*>(src + ((((size_t)(gy << 7) + gx)) << 6) + (ck << 3));
    *reinterpret_cast<i32x4*>(&lds[(pix << 6) + ((ck ^ (pix & 7)) << 3)]) = v;
  }

  const int wid  = tid >> 6;
  const int lane = tid & 63;
  const int ob16 = ocb64 * 4 + wid;
  const int ox = lane & 15;
  const int kg = lane >> 4;

  bf16x8 afrag[9][2];
#pragma unroll
  for (int t = 0; t < 9; t++)
#pragma unroll
    for (int c = 0; c < 2; c++)
      afrag[t][c] = __builtin_bit_cast(bf16x8,
        *reinterpret_cast<const i32x4*>(wp + ((((t * NOB16 + ob16) * 2 + c) << 9) + (lane << 3))));

  const int rbase = ocb64 * 64 + wid * 16 + (kg << 2);
  f32x4 binit;
#pragma unroll
  for (int r = 0; r < 4; r++) binit[r] = bias[rbase + r];
  f32x4 acc[16];
#pragma unroll
  for (int i = 0; i < 16; i++) acc[i] = binit;

  __syncthreads();

#pragma unroll
  for (int iy = 0; iy < 18; iy++) {
    bf16x8 bfrag[3][2];
#pragma unroll
    for (int dx = 0; dx < 3; dx++) {
      const int p = iy * 18 + ox + dx;
#pragma unroll
      for (int c = 0; c < 2; c++) {
        const int kc = (c << 2) + kg;
        bfrag[dx][c] = __builtin_bit_cast(bf16x8,
          *reinterpret_cast<const i32x4*>(&lds[(p << 6) + ((kc ^ (p & 7)) << 3)]));
      }
    }
#pragma unroll
    for (int dy = 0; dy < 3; dy++) {
      const int oy = iy - dy;
      if (oy >= 0 && oy < 16) {
#pragma unroll
        for (int dx = 0; dx < 3; dx++)
#pragma unroll
          for (int c = 0; c < 2; c++)
            acc[oy] = __builtin_amdgcn_mfma_f32_16x16x32_bf16(
                afrag[dy * 3 + dx][c], bfrag[dx][c], acc[oy], 0, 0, 0);
      }
    }
  }

#pragma unroll
  for (int oy = 0; oy < 16; oy++) {
    const int pix = ((ty0 + oy) << 7) + tx0 + ox;
#pragma unroll
    for (int r = 0; r < 4; r++)
      out[(((size_t)(f * OC + rbase + r)) << 14) + pix] = acc[oy][r];
  }
}

// ---------------- launcher ----------------
extern "C" void kernel_launch(void* const* d_in, const int* in_sizes, int n_in,
                              void* d_out, int out_size, void* d_ws, size_t ws_size,
                              hipStream_t stream) {
  const int*   xy  = (const int*)d_in[0];
  const float* t   = (const float*)d_in[1];
  const float* p   = (const float*)d_in[2];
  const float* w1  = (const float*)d_in[5];
  const float* b1  = (const float*)d_in[6];
  const float* g1s = (const float*)d_in[7];
  const float* g1b = (const float*)d_in[8];
  const float* w2  = (const float*)d_in[9];
  const float* b2  = (const float*)d_in[10];
  const float* g2s = (const float*)d_in[11];
  const float* g2b = (const float*)d_in[12];
  const float* w3  = (const float*)d_in[13];
  const float* b3  = (const float*)d_in[14];
  float* out = (float*)d_out;

  const size_t repN = (size_t)NFR * 5 * HW;   // 1,310,720 floats
  const size_t hN   = (size_t)NFR * 64 * HW;  // 16,777,216 elements

  float* ws      = (float*)d_ws;
  float* rep     = ws;
  unsigned* mm_u = (unsigned*)(ws + repN);   // 64 slots (32 used)
  float* statsA  = ws + repN + 64;           // 256 floats
  float* statsB  = statsA + 256;             // 256 floats
  short* wpk2    = (short*)(statsB + 256);
  short* wpk3    = wpk2 + 9 * 4 * 2 * 512;
  short* h2bf    = wpk3 + 9 * 16 * 2 * 512;
  const size_t base_bytes = (repN + 576) * 4 + (36864 + 147456 + hN) * 2;
  short* h1bf;
  if (ws_size >= base_bytes + hN * 2) {
    h1bf = h2bf + hN;
  } else {
    h1bf = (short*)(out + 2 * hN);           // out-tail scratch, dead before conv3
  }
  float* h1f = out;
  float* h2f = out + hN;

  dim3 b256(256);
  init_kernel<<<1024, b256, 0, stream>>>(rep, mm_u, statsA, statsB);
  minmax_kernel<<<NFR * 32, b256, 0, stream>>>(t, mm_u);
  scatter_kernel<<<(NFR * NEV + 255) / 256, b256, 0, stream>>>(xy, t, p, mm_u, rep);
  norm_counts_kernel<<<NFR * 2, b256, 0, stream>>>(rep);

  repack_w_kernel<64><<<(9 * 4 * 2 * 512 + 255) / 256, b256, 0, stream>>>(w2, wpk2);
  repack_w_kernel<256><<<(9 * 16 * 2 * 512 + 255) / 256, b256, 0, stream>>>(w3, wpk3);

  conv1_kernel<<<dim3(8, 8, NFR), b256, 0, stream>>>(rep, w1, b1, h1f);

  gn_stats_kernel<<<NFR * 8 * 8, b256, 0, stream>>>(h1f, statsA);
  gn_gelu_t_kernel<<<NFR * 64, b256, 0, stream>>>(h1f, statsA, g1s, g1b, h1bf);

  conv_mfma_kernel<64><<<dim3(8, 8, NFR), b256, 0, stream>>>(h1bf, wpk2, b2, h2f);

  gn_stats_kernel<<<NFR * 8 * 8, b256, 0, stream>>>(h2f, statsB);
  gn_gelu_t_kernel<<<NFR * 64, b256, 0, stream>>>(h2f, statsB, g2s, g2b, h2bf);

  conv_mfma_kernel<256><<<dim3(8, 8, NFR * 4), b256, 0, stream>>>(h2bf, wpk3, b3, out);
}